// Round 2
// baseline (85.884 us; speedup 1.0000x reference)
//
#include <hip/hip_runtime.h>

// Problem constants
#define X_RANGE 256
#define Y_RANGE 256
#define NUM_ANGLES 180
#define NUM_DET 512
#define BATCH 8
#define M_ROWS (BATCH * NUM_ANGLES)      // 1440
#define K_DIM NUM_DET                    // 512
#define N_DIM NUM_DET                    // 512
#define AD (NUM_ANGLES * NUM_DET)        // 92160
#define NPIX (X_RANGE * Y_RANGE)         // 65536
#define NITER (NUM_ANGLES / 4)           // 45 vec4 iterations over angles

// ---------------- Kernel 1: filter GEMM (unchanged from R1) ----------------
// out[m][e] = sum_d A[m][d] * W[e][d]   (both operands K-contiguous)
// m = b*180 + a, so out row-major == flat [b][a*512+e] layout the gather needs.
#define BM 64
#define BN 64
#define BK 32

__global__ __launch_bounds__(256) void filter_gemm(const float* __restrict__ A,
                                                   const float* __restrict__ Wm,
                                                   float* __restrict__ outF) {
    __shared__ float As[BK][BM];   // transposed: As[k][m]
    __shared__ float Bs[BK][BN];   // transposed: Bs[k][n]
    const int tid = threadIdx.x;
    const int tx = tid & 15;       // n direction (4 cols each)
    const int ty = tid >> 4;       // m direction (4 rows each)
    const int mBase = blockIdx.x * BM;
    const int nBase = blockIdx.y * BN;

    float acc[4][4] = {};

    for (int k0 = 0; k0 < K_DIM; k0 += BK) {
#pragma unroll
        for (int l = 0; l < 2; ++l) {
            const int lin = tid + l * 256;
            const int r  = lin >> 3;       // row within tile (m or n), 0..63
            const int kq = lin & 7;        // which float4 along k
            const int gm = mBase + r;
            float4 v = make_float4(0.f, 0.f, 0.f, 0.f);
            if (gm < M_ROWS)
                v = *reinterpret_cast<const float4*>(A + (size_t)gm * K_DIM + k0 + (kq << 2));
            As[(kq << 2) + 0][r] = v.x;
            As[(kq << 2) + 1][r] = v.y;
            As[(kq << 2) + 2][r] = v.z;
            As[(kq << 2) + 3][r] = v.w;
            const float4 w = *reinterpret_cast<const float4*>(
                Wm + (size_t)(nBase + r) * K_DIM + k0 + (kq << 2));
            Bs[(kq << 2) + 0][r] = w.x;
            Bs[(kq << 2) + 1][r] = w.y;
            Bs[(kq << 2) + 2][r] = w.z;
            Bs[(kq << 2) + 3][r] = w.w;
        }
        __syncthreads();
#pragma unroll
        for (int k = 0; k < BK; ++k) {
            const float4 a4 = *reinterpret_cast<const float4*>(&As[k][ty << 2]);
            const float4 b4 = *reinterpret_cast<const float4*>(&Bs[k][tx << 2]);
            const float av[4] = {a4.x, a4.y, a4.z, a4.w};
            const float bv[4] = {b4.x, b4.y, b4.z, b4.w};
#pragma unroll
            for (int i = 0; i < 4; ++i)
#pragma unroll
                for (int j = 0; j < 4; ++j)
                    acc[i][j] += av[i] * bv[j];
        }
        __syncthreads();
    }

#pragma unroll
    for (int i = 0; i < 4; ++i) {
        const int gm = mBase + (ty << 2) + i;
        if (gm < M_ROWS) {
            const float4 o = make_float4(acc[i][0], acc[i][1], acc[i][2], acc[i][3]);
            *reinterpret_cast<float4*>(outF + (size_t)gm * N_DIM + nBase + (tx << 2)) = o;
        }
    }
}

// ---------------- Kernel 2: gather + weighted backprojection ----------------
// Block = 32 pixels x 8 angle-sub-chunks (256 threads). Sub-chunk `sub` handles
// vec4-iterations i == sub (mod 8) -> 5 or 6 iters each. Partials reduced in
// LDS, written coalesced. Grid 2048 blocks = 8192 waves = 100% occupancy cap.
#define PIXB 32
#define SUBS 8

__global__ __launch_bounds__(256, 8) void backproject(const float* __restrict__ fil,
                                                      const float* __restrict__ wts,
                                                      const int* __restrict__ cm,
                                                      float* __restrict__ out) {
    __shared__ float part[SUBS][PIXB][BATCH];   // 8 KB

    const int tid = threadIdx.x;
    const int pix = tid & (PIXB - 1);
    const int sub = tid >> 5;
    const int p = blockIdx.x * PIXB + pix;      // pixel index, 0..65535

    const int4*   cm4 = reinterpret_cast<const int4*>(cm + (size_t)p * NUM_ANGLES);
    const float4* w4  = reinterpret_cast<const float4*>(wts + (size_t)p * NUM_ANGLES);

    float acc[BATCH] = {};
    for (int i = sub; i < NITER; i += SUBS) {
        const int4   c = cm4[i];
        const float4 w = w4[i];
        const int   idx[4] = {c.x, c.y, c.z, c.w};
        const float wv[4]  = {w.x, w.y, w.z, w.w};
#pragma unroll
        for (int j = 0; j < 4; ++j) {
#pragma unroll
            for (int b = 0; b < BATCH; ++b)
                acc[b] += fil[(size_t)b * AD + idx[j]] * wv[j];
        }
    }

#pragma unroll
    for (int b = 0; b < BATCH; ++b)
        part[sub][pix][b] = acc[b];
    __syncthreads();

    // Reduce over the 8 sub-chunks: thread t -> (b = t>>5, q = t&31).
    const int b = tid >> 5;
    const int q = tid & (PIXB - 1);
    float s = 0.f;
#pragma unroll
    for (int k = 0; k < SUBS; ++k)
        s += part[k][q][b];
    out[(size_t)b * NPIX + blockIdx.x * PIXB + q] = s;
}

extern "C" void kernel_launch(void* const* d_in, const int* in_sizes, int n_in,
                              void* d_out, int out_size, void* d_ws, size_t ws_size,
                              hipStream_t stream) {
    const float* sino = (const float*)d_in[0];   // [8,1,180,512] f32
    const float* Wm   = (const float*)d_in[1];   // [512,512] f32
    const float* wts  = (const float*)d_in[2];   // [1,1,256,256,180] f32
    const int*   cm   = (const int*)d_in[3];     // [256,256,180] i32
    float* out = (float*)d_out;                  // [8,1,256,256] f32
    float* fil = (float*)d_ws;                   // 1440*512 f32 = 2.95 MB scratch

    dim3 gridG((M_ROWS + BM - 1) / BM, N_DIM / BN);   // 23 x 8
    filter_gemm<<<gridG, dim3(256), 0, stream>>>(sino, Wm, fil);

    backproject<<<NPIX / PIXB, 256, 0, stream>>>(fil, wts, cm, out);
}

// Round 3
// 74.549 us; speedup vs baseline: 1.1520x; 1.1520x over previous
//
#include <hip/hip_runtime.h>

// Problem constants
#define X_RANGE 256
#define Y_RANGE 256
#define NUM_ANGLES 180
#define NUM_DET 512
#define BATCH 8
#define M_ROWS (BATCH * NUM_ANGLES)      // 1440
#define K_DIM NUM_DET                    // 512
#define N_DIM NUM_DET                    // 512
#define AD (NUM_ANGLES * NUM_DET)        // 92160
#define NPIX (X_RANGE * Y_RANGE)         // 65536
#define NITER (NUM_ANGLES / 4)           // 45 vec4 iterations over angles

// ---------------- Kernel 1: filter GEMM, epilogue transposes to batch-inner ----------------
// acc[m][e] = sum_d A[m][d] * W[e][d], m = b*180 + a.
// Output layout: filT[(a*512 + e)*8 + b]  -> the 8 batch values of one (angle,det)
// bin are contiguous (32 B), so the backprojection gathers float4s.
#define BM 64
#define BN 64
#define BK 32

__global__ __launch_bounds__(256) void filter_gemm(const float* __restrict__ A,
                                                   const float* __restrict__ Wm,
                                                   float* __restrict__ filT) {
    __shared__ float As[BK][BM];   // transposed: As[k][m]
    __shared__ float Bs[BK][BN];   // transposed: Bs[k][n]
    const int tid = threadIdx.x;
    const int tx = tid & 15;       // n direction (4 cols each)
    const int ty = tid >> 4;       // m direction (4 rows each)
    const int mBase = blockIdx.x * BM;
    const int nBase = blockIdx.y * BN;

    float acc[4][4] = {};

    for (int k0 = 0; k0 < K_DIM; k0 += BK) {
#pragma unroll
        for (int l = 0; l < 2; ++l) {
            const int lin = tid + l * 256;
            const int r  = lin >> 3;       // row within tile (m or n), 0..63
            const int kq = lin & 7;        // which float4 along k
            const int gm = mBase + r;
            float4 v = make_float4(0.f, 0.f, 0.f, 0.f);
            if (gm < M_ROWS)
                v = *reinterpret_cast<const float4*>(A + (size_t)gm * K_DIM + k0 + (kq << 2));
            As[(kq << 2) + 0][r] = v.x;
            As[(kq << 2) + 1][r] = v.y;
            As[(kq << 2) + 2][r] = v.z;
            As[(kq << 2) + 3][r] = v.w;
            const float4 w = *reinterpret_cast<const float4*>(
                Wm + (size_t)(nBase + r) * K_DIM + k0 + (kq << 2));
            Bs[(kq << 2) + 0][r] = w.x;
            Bs[(kq << 2) + 1][r] = w.y;
            Bs[(kq << 2) + 2][r] = w.z;
            Bs[(kq << 2) + 3][r] = w.w;
        }
        __syncthreads();
#pragma unroll
        for (int k = 0; k < BK; ++k) {
            const float4 a4 = *reinterpret_cast<const float4*>(&As[k][ty << 2]);
            const float4 b4 = *reinterpret_cast<const float4*>(&Bs[k][tx << 2]);
            const float av[4] = {a4.x, a4.y, a4.z, a4.w};
            const float bv[4] = {b4.x, b4.y, b4.z, b4.w};
#pragma unroll
            for (int i = 0; i < 4; ++i)
#pragma unroll
                for (int j = 0; j < 4; ++j)
                    acc[i][j] += av[i] * bv[j];
        }
        __syncthreads();
    }

    // Transposing epilogue: filT[(a*512 + e)*8 + b]
#pragma unroll
    for (int i = 0; i < 4; ++i) {
        const int gm = mBase + (ty << 2) + i;
        if (gm < M_ROWS) {
            const int b = gm / NUM_ANGLES;
            const int a = gm - b * NUM_ANGLES;
            const size_t base = ((size_t)a * N_DIM + nBase + (tx << 2)) * BATCH + b;
#pragma unroll
            for (int j = 0; j < 4; ++j)
                filT[base + (size_t)j * BATCH] = acc[i][j];
        }
    }
}

// ---------------- Kernel 2: gather + weighted backprojection ----------------
// Block = 32 pixels x 8 angle-sub-chunks (256 threads). Per (pixel, angle) the
// 8 batch values are 2 contiguous float4s -> 8 independent 16B gathers/iter.
#define PIXB 32
#define SUBS 8

__global__ __launch_bounds__(256, 4) void backproject(const float* __restrict__ filT,
                                                      const float* __restrict__ wts,
                                                      const int* __restrict__ cm,
                                                      float* __restrict__ out) {
    __shared__ float part[SUBS][PIXB][BATCH + 1];   // +1 pad: kill 8-way bank conflict

    const int tid = threadIdx.x;
    const int pix = tid & (PIXB - 1);
    const int sub = tid >> 5;
    const int p = blockIdx.x * PIXB + pix;      // pixel index, 0..65535

    const int4*   cm4 = reinterpret_cast<const int4*>(cm + (size_t)p * NUM_ANGLES);
    const float4* w4  = reinterpret_cast<const float4*>(wts + (size_t)p * NUM_ANGLES);

    float4 accLo = make_float4(0.f, 0.f, 0.f, 0.f);   // batches 0..3
    float4 accHi = make_float4(0.f, 0.f, 0.f, 0.f);   // batches 4..7

    int i = sub;
    int4   c = cm4[i];
    float4 w = w4[i];
    while (true) {
        const int4   cc = c;
        const float4 ww = w;
        i += SUBS;
        const bool more = (i < NITER);
        if (more) { c = cm4[i]; w = w4[i]; }       // prefetch next

        const int   idx[4] = {cc.x, cc.y, cc.z, cc.w};
        const float wv[4]  = {ww.x, ww.y, ww.z, ww.w};
#pragma unroll
        for (int j = 0; j < 4; ++j) {
            const float4 lo = *reinterpret_cast<const float4*>(filT + (size_t)idx[j] * BATCH);
            const float4 hi = *reinterpret_cast<const float4*>(filT + (size_t)idx[j] * BATCH + 4);
            accLo.x += lo.x * wv[j];  accLo.y += lo.y * wv[j];
            accLo.z += lo.z * wv[j];  accLo.w += lo.w * wv[j];
            accHi.x += hi.x * wv[j];  accHi.y += hi.y * wv[j];
            accHi.z += hi.z * wv[j];  accHi.w += hi.w * wv[j];
        }
        if (!more) break;
    }

    part[sub][pix][0] = accLo.x;  part[sub][pix][1] = accLo.y;
    part[sub][pix][2] = accLo.z;  part[sub][pix][3] = accLo.w;
    part[sub][pix][4] = accHi.x;  part[sub][pix][5] = accHi.y;
    part[sub][pix][6] = accHi.z;  part[sub][pix][7] = accHi.w;
    __syncthreads();

    // Reduce over the 8 sub-chunks: thread t -> (b = t>>5, q = t&31).
    const int b = tid >> 5;
    const int q = tid & (PIXB - 1);
    float s = 0.f;
#pragma unroll
    for (int k = 0; k < SUBS; ++k)
        s += part[k][q][b];
    out[(size_t)b * NPIX + blockIdx.x * PIXB + q] = s;
}

extern "C" void kernel_launch(void* const* d_in, const int* in_sizes, int n_in,
                              void* d_out, int out_size, void* d_ws, size_t ws_size,
                              hipStream_t stream) {
    const float* sino = (const float*)d_in[0];   // [8,1,180,512] f32
    const float* Wm   = (const float*)d_in[1];   // [512,512] f32
    const float* wts  = (const float*)d_in[2];   // [1,1,256,256,180] f32
    const int*   cm   = (const int*)d_in[3];     // [256,256,180] i32
    float* out = (float*)d_out;                  // [8,1,256,256] f32
    float* filT = (float*)d_ws;                  // [92160][8] f32 = 2.95 MB scratch

    dim3 gridG((M_ROWS + BM - 1) / BM, N_DIM / BN);   // 23 x 8
    filter_gemm<<<gridG, dim3(256), 0, stream>>>(sino, Wm, filT);

    backproject<<<NPIX / PIXB, 256, 0, stream>>>(filT, wts, cm, out);
}

// Round 4
// 70.385 us; speedup vs baseline: 1.2202x; 1.0592x over previous
//
#include <hip/hip_runtime.h>

// Problem constants
#define X_RANGE 256
#define Y_RANGE 256
#define NUM_ANGLES 180
#define NUM_DET 512
#define BATCH 8
#define M_ROWS (BATCH * NUM_ANGLES)      // 1440
#define K_DIM NUM_DET                    // 512
#define N_DIM NUM_DET                    // 512
#define AD (NUM_ANGLES * NUM_DET)        // 92160
#define NPIX (X_RANGE * Y_RANGE)         // 65536
#define NITER (NUM_ANGLES / 4)           // 45 vec4 iterations over angles
#define MN ((size_t)M_ROWS * N_DIM)      // 737280

// ---------------- Kernel 1a: filter GEMM, K-split x2, coalesced output ----------------
// partial[z][m][e] = sum_{d in half z} A[m][d] * W[e][d]
#define BM 64
#define BN 64
#define BK 32

__global__ __launch_bounds__(256) void filter_gemm_ks(const float* __restrict__ A,
                                                      const float* __restrict__ Wm,
                                                      float* __restrict__ outP) {
    __shared__ float As[BK][BM];
    __shared__ float Bs[BK][BN];
    const int tid = threadIdx.x;
    const int tx = tid & 15;
    const int ty = tid >> 4;
    const int mBase = blockIdx.x * BM;
    const int nBase = blockIdx.y * BN;
    const int kz = blockIdx.z;                       // 0 or 1
    float* outF = outP + (size_t)kz * MN;

    float acc[4][4] = {};

    for (int k0 = kz * 256; k0 < kz * 256 + 256; k0 += BK) {
#pragma unroll
        for (int l = 0; l < 2; ++l) {
            const int lin = tid + l * 256;
            const int r  = lin >> 3;
            const int kq = lin & 7;
            const int gm = mBase + r;
            float4 v = make_float4(0.f, 0.f, 0.f, 0.f);
            if (gm < M_ROWS)
                v = *reinterpret_cast<const float4*>(A + (size_t)gm * K_DIM + k0 + (kq << 2));
            As[(kq << 2) + 0][r] = v.x;
            As[(kq << 2) + 1][r] = v.y;
            As[(kq << 2) + 2][r] = v.z;
            As[(kq << 2) + 3][r] = v.w;
            const float4 w = *reinterpret_cast<const float4*>(
                Wm + (size_t)(nBase + r) * K_DIM + k0 + (kq << 2));
            Bs[(kq << 2) + 0][r] = w.x;
            Bs[(kq << 2) + 1][r] = w.y;
            Bs[(kq << 2) + 2][r] = w.z;
            Bs[(kq << 2) + 3][r] = w.w;
        }
        __syncthreads();
#pragma unroll
        for (int k = 0; k < BK; ++k) {
            const float4 a4 = *reinterpret_cast<const float4*>(&As[k][ty << 2]);
            const float4 b4 = *reinterpret_cast<const float4*>(&Bs[k][tx << 2]);
            const float av[4] = {a4.x, a4.y, a4.z, a4.w};
            const float bv[4] = {b4.x, b4.y, b4.z, b4.w};
#pragma unroll
            for (int i = 0; i < 4; ++i)
#pragma unroll
                for (int j = 0; j < 4; ++j)
                    acc[i][j] += av[i] * bv[j];
        }
        __syncthreads();
    }

#pragma unroll
    for (int i = 0; i < 4; ++i) {
        const int gm = mBase + (ty << 2) + i;
        if (gm < M_ROWS) {
            const float4 o = make_float4(acc[i][0], acc[i][1], acc[i][2], acc[i][3]);
            *reinterpret_cast<float4*>(outF + (size_t)gm * N_DIM + nBase + (tx << 2)) = o;
        }
    }
}

// ---------------- Kernel 1b: transpose (b outer -> b inner) + sum K-partials ----------------
// filT[(a*512+e)*8 + b] = f0[b][ae] + f1[b][ae]; reads coalesced along ae, writes
// two contiguous float4 per thread (fully coalesced in aggregate).
__global__ __launch_bounds__(256) void transpose_sum(const float* __restrict__ f0,
                                                     const float* __restrict__ f1,
                                                     float* __restrict__ filT) {
    const int ae = blockIdx.x * 256 + threadIdx.x;   // 0..92159
    float v[8];
#pragma unroll
    for (int b = 0; b < 8; ++b)
        v[b] = f0[(size_t)b * AD + ae] + f1[(size_t)b * AD + ae];
    *reinterpret_cast<float4*>(filT + (size_t)ae * 8)     = make_float4(v[0], v[1], v[2], v[3]);
    *reinterpret_cast<float4*>(filT + (size_t)ae * 8 + 4) = make_float4(v[4], v[5], v[6], v[7]);
}

// ---------------- Kernel 1-fallback: scatter-epilogue GEMM (if ws too small) ----------------
__global__ __launch_bounds__(256) void filter_gemm_scatter(const float* __restrict__ A,
                                                           const float* __restrict__ Wm,
                                                           float* __restrict__ filT) {
    __shared__ float As[BK][BM];
    __shared__ float Bs[BK][BN];
    const int tid = threadIdx.x;
    const int tx = tid & 15;
    const int ty = tid >> 4;
    const int mBase = blockIdx.x * BM;
    const int nBase = blockIdx.y * BN;
    float acc[4][4] = {};
    for (int k0 = 0; k0 < K_DIM; k0 += BK) {
#pragma unroll
        for (int l = 0; l < 2; ++l) {
            const int lin = tid + l * 256;
            const int r  = lin >> 3;
            const int kq = lin & 7;
            const int gm = mBase + r;
            float4 v = make_float4(0.f, 0.f, 0.f, 0.f);
            if (gm < M_ROWS)
                v = *reinterpret_cast<const float4*>(A + (size_t)gm * K_DIM + k0 + (kq << 2));
            As[(kq << 2) + 0][r] = v.x;  As[(kq << 2) + 1][r] = v.y;
            As[(kq << 2) + 2][r] = v.z;  As[(kq << 2) + 3][r] = v.w;
            const float4 w = *reinterpret_cast<const float4*>(
                Wm + (size_t)(nBase + r) * K_DIM + k0 + (kq << 2));
            Bs[(kq << 2) + 0][r] = w.x;  Bs[(kq << 2) + 1][r] = w.y;
            Bs[(kq << 2) + 2][r] = w.z;  Bs[(kq << 2) + 3][r] = w.w;
        }
        __syncthreads();
#pragma unroll
        for (int k = 0; k < BK; ++k) {
            const float4 a4 = *reinterpret_cast<const float4*>(&As[k][ty << 2]);
            const float4 b4 = *reinterpret_cast<const float4*>(&Bs[k][tx << 2]);
            const float av[4] = {a4.x, a4.y, a4.z, a4.w};
            const float bv[4] = {b4.x, b4.y, b4.z, b4.w};
#pragma unroll
            for (int i = 0; i < 4; ++i)
#pragma unroll
                for (int j = 0; j < 4; ++j)
                    acc[i][j] += av[i] * bv[j];
        }
        __syncthreads();
    }
#pragma unroll
    for (int i = 0; i < 4; ++i) {
        const int gm = mBase + (ty << 2) + i;
        if (gm < M_ROWS) {
            const int b = gm / NUM_ANGLES;
            const int a = gm - b * NUM_ANGLES;
            const size_t base = ((size_t)a * N_DIM + nBase + (tx << 2)) * BATCH + b;
#pragma unroll
            for (int j = 0; j < 4; ++j)
                filT[base + (size_t)j * BATCH] = acc[i][j];
        }
    }
}

// ---------------- Kernel 2: gather + weighted backprojection ----------------
// Block = 16 pixels x 16 angle-subchunks, tid = pix*16 + sub so consecutive
// lanes read CONSECUTIVE int4/float4 of one pixel's cm/wts row (coalesced
// streaming: 4 x 256B contiguous chunks per wave instruction).
// Per (pixel,angle): 8 batch floats = 2 contiguous float4 gathers (one 32B line).
// All streaming loads issued upfront; gathers in named vars, 2 stages in flight.
#define PIXB 16
#define SUBS 16

__device__ __forceinline__ void fma8(float4& aL, float4& aH,
                                     const float4 lo, const float4 hi, const float wv) {
    aL.x += lo.x * wv;  aL.y += lo.y * wv;  aL.z += lo.z * wv;  aL.w += lo.w * wv;
    aH.x += hi.x * wv;  aH.y += hi.y * wv;  aH.z += hi.z * wv;  aH.w += hi.w * wv;
}

#define GATHER8(c_, L0,H0,L1,H1,L2,H2,L3,H3)                                  \
    L0 = *reinterpret_cast<const float4*>(filT + (size_t)(c_).x * BATCH);     \
    H0 = *reinterpret_cast<const float4*>(filT + (size_t)(c_).x * BATCH + 4); \
    L1 = *reinterpret_cast<const float4*>(filT + (size_t)(c_).y * BATCH);     \
    H1 = *reinterpret_cast<const float4*>(filT + (size_t)(c_).y * BATCH + 4); \
    L2 = *reinterpret_cast<const float4*>(filT + (size_t)(c_).z * BATCH);     \
    H2 = *reinterpret_cast<const float4*>(filT + (size_t)(c_).z * BATCH + 4); \
    L3 = *reinterpret_cast<const float4*>(filT + (size_t)(c_).w * BATCH);     \
    H3 = *reinterpret_cast<const float4*>(filT + (size_t)(c_).w * BATCH + 4);

__global__ __launch_bounds__(256, 4) void backproject(const float* __restrict__ filT,
                                                      const float* __restrict__ wts,
                                                      const int* __restrict__ cm,
                                                      float* __restrict__ out) {
    __shared__ float part[PIXB][SUBS][9];   // [pix][sub][b], pad -> conflict-free stores

    const int tid  = threadIdx.x;
    const int sub  = tid & (SUBS - 1);
    const int pixL = tid >> 4;
    const int p    = blockIdx.x * PIXB + pixL;

    const int4*   cm4 = reinterpret_cast<const int4*>(cm + (size_t)p * NUM_ANGLES);
    const float4* w4  = reinterpret_cast<const float4*>(wts + (size_t)p * NUM_ANGLES);

    // 45 = 16*2 + 13 -> subs 0..12 run 3 stages, subs 13..15 run 2.
    const bool has2 = (sub < NITER - 2 * SUBS);
    const int4   c0 = cm4[sub];
    const float4 w0 = w4[sub];
    const int4   c1 = cm4[sub + SUBS];
    const float4 w1 = w4[sub + SUBS];
    int4   c2 = make_int4(0, 0, 0, 0);
    float4 w2 = make_float4(0.f, 0.f, 0.f, 0.f);
    if (has2) { c2 = cm4[sub + 2 * SUBS]; w2 = w4[sub + 2 * SUBS]; }

    float4 aL = make_float4(0,0,0,0), aH = make_float4(0,0,0,0);   // chain A
    float4 bL = make_float4(0,0,0,0), bH = make_float4(0,0,0,0);   // chain B

    float4 A0l,A0h,A1l,A1h,A2l,A2h,A3l,A3h;
    float4 B0l,B0h,B1l,B1h,B2l,B2h,B3l,B3h;

    GATHER8(c0, A0l,A0h,A1l,A1h,A2l,A2h,A3l,A3h);   // stage 0
    GATHER8(c1, B0l,B0h,B1l,B1h,B2l,B2h,B3l,B3h);   // stage 1 (in flight)

    fma8(aL, aH, A0l, A0h, w0.x);
    fma8(aL, aH, A1l, A1h, w0.y);
    fma8(aL, aH, A2l, A2h, w0.z);
    fma8(aL, aH, A3l, A3h, w0.w);

    GATHER8(c2, A0l,A0h,A1l,A1h,A2l,A2h,A3l,A3h);   // stage 2 (w2=0 if !has2)

    fma8(bL, bH, B0l, B0h, w1.x);
    fma8(bL, bH, B1l, B1h, w1.y);
    fma8(bL, bH, B2l, B2h, w1.z);
    fma8(bL, bH, B3l, B3h, w1.w);

    fma8(aL, aH, A0l, A0h, w2.x);
    fma8(aL, aH, A1l, A1h, w2.y);
    fma8(aL, aH, A2l, A2h, w2.z);
    fma8(aL, aH, A3l, A3h, w2.w);

    part[pixL][sub][0] = aL.x + bL.x;
    part[pixL][sub][1] = aL.y + bL.y;
    part[pixL][sub][2] = aL.z + bL.z;
    part[pixL][sub][3] = aL.w + bL.w;
    part[pixL][sub][4] = aH.x + bH.x;
    part[pixL][sub][5] = aH.y + bH.y;
    part[pixL][sub][6] = aH.z + bH.z;
    part[pixL][sub][7] = aH.w + bH.w;
    __syncthreads();

    // Reduce 16 partials: 128 threads, (q = pixel, b = batch).
    if (tid < PIXB * BATCH) {
        const int b = tid & 7;
        const int q = tid >> 3;
        float s = 0.f;
#pragma unroll
        for (int k = 0; k < SUBS; ++k)
            s += part[q][k][b];
        out[(size_t)b * NPIX + blockIdx.x * PIXB + q] = s;
    }
}

extern "C" void kernel_launch(void* const* d_in, const int* in_sizes, int n_in,
                              void* d_out, int out_size, void* d_ws, size_t ws_size,
                              hipStream_t stream) {
    const float* sino = (const float*)d_in[0];   // [8,1,180,512] f32
    const float* Wm   = (const float*)d_in[1];   // [512,512] f32
    const float* wts  = (const float*)d_in[2];   // [1,1,256,256,180] f32
    const int*   cm   = (const int*)d_in[3];     // [256,256,180] i32
    float* out = (float*)d_out;                  // [8,1,256,256] f32
    float* ws  = (float*)d_ws;

    const size_t need = 3 * MN * sizeof(float);  // 8.85 MB
    const float* filT;
    if (ws_size >= need) {
        float* f0 = ws;            // partial k-half 0, [m][e]
        float* f1 = ws + MN;       // partial k-half 1
        float* ft = ws + 2 * MN;   // filT [ae][b]
        filter_gemm_ks<<<dim3((M_ROWS + BM - 1) / BM, N_DIM / BN, 2), dim3(256), 0, stream>>>(sino, Wm, ws);
        transpose_sum<<<AD / 256, 256, 0, stream>>>(f0, f1, ft);
        filT = ft;
    } else {
        filter_gemm_scatter<<<dim3((M_ROWS + BM - 1) / BM, N_DIM / BN), dim3(256), 0, stream>>>(sino, Wm, ws);
        filT = ws;
    }

    backproject<<<NPIX / PIXB, 256, 0, stream>>>(filT, wts, cm, out);
}